// Round 2
// baseline (138.343 us; speedup 1.0000x reference)
//
#include <hip/hip_runtime.h>

// CTC greedy decode + CTC loss. B=1024, T=256, V=64, blank=63.
// K1: per-(b,t) argmax + log2-sum-exp + p_blank  (HBM-bound streaming)
// K2: per-row single-wave: labels/lengths + prob-domain forward DP with
//     exact power-of-2 renormalization (Rabiner scaling), alphas in regs,
//     8 states/lane, one __shfl_up per step, no barriers.
//
// ws layout: [0, 2MB)        float2 {lse2, pblank}[B*T]
//            [2MB, 2.25MB)   uchar  pred[B*T]
// out: [0,B*T) labels(float) | [B*T,+B) lengths | [B*T+B,+B) probability

#define BB 1024
#define TT 256
#define VV 64
#define BLANKC 63
#define K_LOG2E 1.44269504088896340736f

__global__ __launch_bounds__(256) void k1_decode(const float* __restrict__ logits,
                                                 float2* __restrict__ lsepb,
                                                 unsigned char* __restrict__ pred)
{
    const int gid = blockIdx.x * 256 + threadIdx.x;          // flat (b,t)
    const float4* rp = (const float4*)(logits + (size_t)gid * VV);
    float4 v[16];
    #pragma unroll
    for (int i = 0; i < 16; ++i) v[i] = rp[i];

    float m = v[0].x; int idx = 0;                            // first-max semantics
    #pragma unroll
    for (int i = 0; i < 16; ++i) {
        if (v[i].x > m) { m = v[i].x; idx = 4*i+0; }
        if (v[i].y > m) { m = v[i].y; idx = 4*i+1; }
        if (v[i].z > m) { m = v[i].z; idx = 4*i+2; }
        if (v[i].w > m) { m = v[i].w; idx = 4*i+3; }
    }
    float s0=0.f, s1=0.f, s2=0.f, s3=0.f;
    #pragma unroll
    for (int i = 0; i < 16; ++i) {
        s0 += exp2f((v[i].x - m) * K_LOG2E);
        s1 += exp2f((v[i].y - m) * K_LOG2E);
        s2 += exp2f((v[i].z - m) * K_LOG2E);
        s3 += exp2f((v[i].w - m) * K_LOG2E);
    }
    const float s = (s0 + s1) + (s2 + s3);
    const float lse2 = m * K_LOG2E + log2f(s);                // log2(sum exp)
    const float pb   = exp2f(fmaf(v[15].w, K_LOG2E, -lse2));  // P(blank)
    lsepb[gid] = make_float2(lse2, pb);
    pred[gid]  = (unsigned char)idx;
}

// one DP step: update 8 (+1) states from buffered x (4 label logits) and {lse2,pb}
#define STEP(XV, LS) { \
    const float lse2 = (LS).x, pbv = (LS).y; \
    const float q0 = exp2f(fmaf((XV)[0], K_LOG2E, -lse2)); \
    const float q1 = exp2f(fmaf((XV)[1], K_LOG2E, -lse2)); \
    const float q2 = exp2f(fmaf((XV)[2], K_LOG2E, -lse2)); \
    const float q3 = exp2f(fmaf((XV)[3], K_LOG2E, -lse2)); \
    float nb = __shfl_up(a7, 1, 64); nb = (lane == 0) ? 0.0f : nb; \
    const float na0 = (a0 + nb) * pbv; \
    const float na1 = (a1 + a0 + sk0 * nb) * q0; \
    const float na2 = (a2 + a1) * pbv; \
    const float na3 = (a3 + a2 + sk1 * a1) * q1; \
    const float na4 = (a4 + a3) * pbv; \
    const float na5 = (a5 + a4 + sk2 * a3) * q2; \
    const float na6 = (a6 + a5) * pbv; \
    const float na7 = (a7 + a6 + sk3 * a5) * q3; \
    a8 = (a8 + a7) * pbv; \
    a0 = na0; a1 = na1; a2 = na2; a3 = na3; \
    a4 = na4; a5 = na5; a6 = na6; a7 = na7; \
}

__global__ __launch_bounds__(64) void k2_dp(const float* __restrict__ logits,
                                            const float2* __restrict__ lsepb,
                                            const unsigned char* __restrict__ pred,
                                            float* __restrict__ out)
{
    __shared__ int    lab_s[TT];
    __shared__ float2 lsepb_s[TT];
    __shared__ float  alpha_s[520];

    const int lane = threadIdx.x;
    const int b    = blockIdx.x;

    // ---- stage {lse2,pb} row into LDS (coalesced) ----
    {
        const float4* src = (const float4*)(lsepb + (size_t)b * TT);
        float4 u0 = src[2*lane], u1 = src[2*lane + 1];
        ((float4*)lsepb_s)[2*lane]     = u0;
        ((float4*)lsepb_s)[2*lane + 1] = u1;
    }

    // ---- greedy labels: merge repeated, drop blanks (4 preds per lane) ----
    uchar4 pc = ((const uchar4*)(pred + (size_t)b * TT))[lane];
    const int p0 = pc.x, p1 = pc.y, p2 = pc.z, p3 = pc.w;
    int pl = __shfl_up(p3, 1, 64); if (lane == 0) pl = -1;
    const int k0 = (p0 != BLANKC && p0 != pl);
    const int k1 = (p1 != BLANKC && p1 != p0);
    const int k2 = (p2 != BLANKC && p2 != p1);
    const int k3 = (p3 != BLANKC && p3 != p2);
    const int cnt = k0 + k1 + k2 + k3;
    int sc = cnt;
    #pragma unroll
    for (int off = 1; off < 64; off <<= 1) {
        int t = __shfl_up(sc, off, 64);
        if (lane >= off) sc += t;
    }
    const int length = __shfl(sc, 63, 64);
    int pos = sc - cnt;
    ((int4*)lab_s)[lane] = make_int4(BLANKC, BLANKC, BLANKC, BLANKC);
    // same-wave LDS ops execute in program order: init-before-scatter is safe
    if (k0) lab_s[pos++] = p0;
    if (k1) lab_s[pos++] = p1;
    if (k2) lab_s[pos++] = p2;
    if (k3) lab_s[pos++] = p3;

    const int4 lq = ((const int4*)lab_s)[lane];   // labels 4j..4j+3
    // labels + lengths outputs
    ((float4*)(out + (size_t)b * TT))[lane] =
        make_float4((float)lq.x, (float)lq.y, (float)lq.z, (float)lq.w);
    if (lane == 0) out[(size_t)BB * TT + b] = (float)length;

    int lprev = __shfl_up(lq.w, 1, 64); if (lane == 0) lprev = BLANKC;
    const float sk0 = (lq.x != BLANKC && lq.x != lprev) ? 1.0f : 0.0f;
    const float sk1 = (lq.y != BLANKC && lq.y != lq.x) ? 1.0f : 0.0f;
    const float sk2 = (lq.z != BLANKC && lq.z != lq.y) ? 1.0f : 0.0f;
    const float sk3 = (lq.w != BLANKC && lq.w != lq.z) ? 1.0f : 0.0f;
    const int vo0 = lq.x, vo1 = lq.y, vo2 = lq.z, vo3 = lq.w;

    // ---- forward DP, prob domain, 8 states/lane + state 512 on lane 63 ----
    float a0=0.f,a1=0.f,a2=0.f,a3=0.f,a4=0.f,a5=0.f,a6=0.f,a7=0.f,a8=0.f;
    if (lane == 0) a0 = 1.0f;
    int E = 0;

    const float* Lt = logits + (size_t)b * (TT * VV);
    float  xA[8][4], xB[8][4];
    float2 lsA[8],  lsB[8];

    #pragma unroll
    for (int u = 0; u < 8; ++u) {                  // preload steps 0..7
        xA[u][0] = Lt[u*64 + vo0]; xA[u][1] = Lt[u*64 + vo1];
        xA[u][2] = Lt[u*64 + vo2]; xA[u][3] = Lt[u*64 + vo3];
        lsA[u] = lsepb_s[u];
    }

    #pragma unroll 1
    for (int tb = 0; tb < 16; ++tb) {              // 16 steps per iter
        const int t0 = tb * 16;
        #pragma unroll
        for (int u = 0; u < 8; ++u) {              // prefetch steps t0+8..15
            const int tt = 8 + u;
            xB[u][0] = Lt[tt*64 + vo0]; xB[u][1] = Lt[tt*64 + vo1];
            xB[u][2] = Lt[tt*64 + vo2]; xB[u][3] = Lt[tt*64 + vo3];
            lsB[u] = lsepb_s[t0 + 8 + u];
        }
        #pragma unroll
        for (int u = 0; u < 8; ++u) STEP(xA[u], lsA[u]);   // steps t0..t0+7

        Lt += 1024;                                 // advance 16 steps
        if (tb < 15) {
            #pragma unroll
            for (int u = 0; u < 8; ++u) {          // prefetch steps t0+16..23
                xA[u][0] = Lt[u*64 + vo0]; xA[u][1] = Lt[u*64 + vo1];
                xA[u][2] = Lt[u*64 + vo2]; xA[u][3] = Lt[u*64 + vo3];
                lsA[u] = lsepb_s[t0 + 16 + u];
            }
        }
        #pragma unroll
        for (int u = 0; u < 8; ++u) STEP(xB[u], lsB[u]);   // steps t0+8..15

        if (tb & 1) {                              // renorm every 32 steps
            float M = fmaxf(fmaxf(fmaxf(a0,a1), fmaxf(a2,a3)),
                            fmaxf(fmaxf(a4,a5), fmaxf(a6,a7)));
            M = fmaxf(M, a8);
            #pragma unroll
            for (int off = 1; off < 64; off <<= 1)
                M = fmaxf(M, __shfl_xor(M, off, 64));
            int e = (int)((__float_as_uint(M) >> 23) & 255) - 127;
            if (M == 0.0f) e = 0;
            const float scl = ldexpf(1.0f, -e);
            E += e;
            a0*=scl; a1*=scl; a2*=scl; a3*=scl; a4*=scl;
            a5*=scl; a6*=scl; a7*=scl; a8*=scl;
        }
    }

    // ---- epilogue: probability = (alpha[end] + alpha[end-1]) * 2^E ----
    ((float4*)alpha_s)[2*lane]     = make_float4(a0, a1, a2, a3);
    ((float4*)alpha_s)[2*lane + 1] = make_float4(a4, a5, a6, a7);
    if (lane == 63) alpha_s[512] = a8;
    if (lane == 0) {
        const int end = 2 * length;
        const float e1 = alpha_s[end];
        const float e2 = (length > 0) ? alpha_s[end - 1] : 0.0f;
        out[(size_t)BB * TT + BB + b] = exp2f(log2f(e1 + e2) + (float)E);
    }
}

extern "C" void kernel_launch(void* const* d_in, const int* in_sizes, int n_in,
                              void* d_out, int out_size, void* d_ws, size_t ws_size,
                              hipStream_t stream)
{
    const float* logits = (const float*)d_in[0];
    float* out = (float*)d_out;
    float2* lsepb = (float2*)d_ws;                                   // 2 MB
    unsigned char* pred = (unsigned char*)d_ws + (size_t)2097152;    // 256 KB
    hipLaunchKernelGGL(k1_decode, dim3(BB * TT / 256), dim3(256), 0, stream,
                       logits, lsepb, pred);
    hipLaunchKernelGGL(k2_dp, dim3(BB), dim3(64), 0, stream,
                       logits, lsepb, pred, out);
}